// Round 11
// baseline (126.072 us; speedup 1.0000x reference)
//
#include <hip/hip_runtime.h>
#include <hip/hip_bf16.h>

typedef __attribute__((ext_vector_type(8))) __bf16 bf16x8;
typedef __attribute__((ext_vector_type(4))) float f32x4;

#define IN_CH 512
#define OUT_CH 64
#define BS 98           // rows per bucket (rowres fits in 7 bits)
#define NB 512          // buckets; BS*NB = 50176 >= N
#define CHUNK 8192      // edges per scatter block (512 thr x 16)
#define CAP 4096        // fixed slots per bucket (mean 3125, +17 sigma)
#define NW 8            // waves per scatter block

__device__ inline unsigned short f2bf(float f) {
    __hip_bfloat16 h = __float2bfloat16(f);
    return __builtin_bit_cast(unsigned short, h);
}
__device__ inline float bf2f(unsigned short u) {
    return __uint_as_float(((unsigned)u) << 16);
}

// ---------------- prep: W -> MFMA B-fragments (bf16) + bcur init -------------
__global__ __launch_bounds__(512) void prep_kernel(
    const float* __restrict__ W, __hip_bfloat16* __restrict__ Wf,
    int* __restrict__ bcur)
{
    const int t = blockIdx.x * 512 + threadIdx.x;   // 0..4095
    if (t < NB) bcur[t] = t * CAP;
    const int ct = t >> 10;          // 0..3
    const int rem = t & 1023;
    const int ks = rem >> 6;         // 0..15
    const int l = rem & 63;          // lane
    const int col = ct * 16 + (l & 15);
    const int kb = ks * 32 + (l >> 4) * 8;
    __hip_bfloat16* dst = Wf + (size_t)t * 8;
    #pragma unroll
    for (int j = 0; j < 8; ++j)
        dst[j] = (__hip_bfloat16)W[(size_t)(kb + j) * OUT_CH + col];
}

// ---------------- GEMM: whole 32-row A-tile staged bf16, single barrier ------
__global__ __launch_bounds__(128) void gemm_kernel(
    const float* __restrict__ A, const bf16x8* __restrict__ wf,
    __hip_bfloat16* __restrict__ outb, int N)
{
    __shared__ __align__(16) char Abf[32 * 1024];   // 32 KB

    const int tid = threadIdx.x;
    const int row0 = blockIdx.x * 32;

    #pragma unroll 1
    for (int ob = 0; ob < 4; ++ob) {
        float4 v[8];
        #pragma unroll
        for (int j = 0; j < 8; ++j) {
            int f = (ob * 8 + j) * 128 + tid;
            int row = f >> 7, c4 = f & 127;
            int rg = row0 + row; rg = rg < N ? rg : N - 1;
            v[j] = *(const float4*)(A + (size_t)rg * IN_CH + c4 * 4);
        }
        #pragma unroll
        for (int j = 0; j < 8; ++j) {
            int f = (ob * 8 + j) * 128 + tid;
            int row = f >> 7, c4 = f & 127;
            int blk = c4 >> 1, half = c4 & 1;
            ushort4 h;
            h.x = f2bf(v[j].x); h.y = f2bf(v[j].y);
            h.z = f2bf(v[j].z); h.w = f2bf(v[j].w);
            *(ushort4*)(Abf + row * 1024 + ((blk ^ (row & 7)) << 4) + (half << 3)) = h;
        }
    }
    __syncthreads();

    const int lane = tid & 63;
    const int wave = tid >> 6;
    const int arow = wave * 16 + (lane & 15);
    const int kgb = lane >> 4;

    bf16x8 a[16];
    #pragma unroll
    for (int ks = 0; ks < 16; ++ks)
        a[ks] = *(const bf16x8*)(Abf + arow * 1024 +
                                 (((ks * 4 + kgb) ^ (arow & 7)) << 4));

    const int colb = lane & 15;
    const int rr = row0 + wave * 16 + (lane >> 4) * 4;
    #pragma unroll 1
    for (int ct = 0; ct < 4; ++ct) {
        bf16x8 w[16];
        #pragma unroll
        for (int ks = 0; ks < 16; ++ks) w[ks] = wf[(ct * 16 + ks) * 64 + lane];
        f32x4 acc = {0.f, 0.f, 0.f, 0.f};
        #pragma unroll
        for (int ks = 0; ks < 16; ++ks)
            acc = __builtin_amdgcn_mfma_f32_16x16x32_bf16(a[ks], w[ks], acc, 0, 0, 0);
        int col = ct * 16 + colb;
        #pragma unroll
        for (int i = 0; i < 4; ++i) {
            int r = rr + i;
            if (r < N)
                outb[(size_t)r * OUT_CH + col] = __float2bfloat16(acc[i]);
        }
    }
}

// ---------------- bucket scatter: per-wave sub-histograms, 6B records --------
// key = (col << 7) | rowres  (col<65536, rowres<128);  val = bf16
__global__ __launch_bounds__(512) void bucket_scatter_kernel(
    const int* __restrict__ rows, const int* __restrict__ cols,
    const float* __restrict__ vals, int* __restrict__ bcur,
    unsigned* __restrict__ segk, unsigned short* __restrict__ segv, int E)
{
    __shared__ int hist[NW][NB];    // 16 KB: counts -> per-wave cursors
    __shared__ int tmpc[NB];        // 2 KB scratch for per-bucket totals
    const int tid = threadIdx.x;
    const int wave = tid >> 6;
    const int base = blockIdx.x * CHUNK + tid * 16;

    #pragma unroll
    for (int w = 0; w < NW; ++w) hist[w][tid] = 0;
    __syncthreads();

    int myb[16]; unsigned mykey[16]; unsigned short myval[16];
    if (base + 16 <= E) {
        int4 r4[4], c4[4]; float4 v4[4];
        #pragma unroll
        for (int q = 0; q < 4; ++q) {
            r4[q] = *(const int4*)(rows + base + q * 4);
            c4[q] = *(const int4*)(cols + base + q * 4);
            v4[q] = *(const float4*)(vals + base + q * 4);
        }
        #pragma unroll
        for (int q = 0; q < 4; ++q) {
            int rr[4] = {r4[q].x, r4[q].y, r4[q].z, r4[q].w};
            int cc[4] = {c4[q].x, c4[q].y, c4[q].z, c4[q].w};
            float vv[4] = {v4[q].x, v4[q].y, v4[q].z, v4[q].w};
            #pragma unroll
            for (int u = 0; u < 4; ++u) {
                int j = q * 4 + u;
                int r = rr[u];
                int b = r / BS;
                myb[j] = b;
                mykey[j] = ((unsigned)cc[u] << 7) | (unsigned)(r - b * BS);
                myval[j] = f2bf(vv[u]);
                atomicAdd(&hist[wave][b], 1);
            }
        }
    } else {
        #pragma unroll
        for (int j = 0; j < 16; ++j) {
            int e = base + j;
            myb[j] = -1;
            if (e < E) {
                int r = rows[e];
                int b = r / BS;
                myb[j] = b;
                mykey[j] = ((unsigned)cols[e] << 7) | (unsigned)(r - b * BS);
                myval[j] = f2bf(vals[e]);
                atomicAdd(&hist[wave][b], 1);
            }
        }
    }
    __syncthreads();

    // thread tid owns bucket tid: total count, one global atomic, per-wave bases
    {
        int c[NW], tot = 0;
        #pragma unroll
        for (int w = 0; w < NW; ++w) { c[w] = hist[w][tid]; tot += c[w]; }
        int b0 = 0;
        if (tot) b0 = atomicAdd(&bcur[tid], tot);
        tmpc[tid] = 0;  // unused sync filler
        int run = b0;
        #pragma unroll
        for (int w = 0; w < NW; ++w) { hist[w][tid] = run; run += c[w]; }
    }
    __syncthreads();

    #pragma unroll
    for (int j = 0; j < 16; ++j) {
        if (myb[j] >= 0) {
            int p = atomicAdd(&hist[wave][myb[j]], 1);
            segk[p] = mykey[j];
            segv[p] = myval[j];
        }
    }
}

// ---------------- per-bucket LDS sort -> 4B compact entries + offs/rend ------
// Output entry: (col << 16) | bf16(val)   (decode: val = asfloat(p<<16))
__global__ __launch_bounds__(512) void sort_kernel(
    const int* __restrict__ bcur,
    const unsigned* __restrict__ segk, const unsigned short* __restrict__ segv,
    unsigned* __restrict__ segc,
    int* __restrict__ offs, int* __restrict__ rend)
{
    __shared__ unsigned sorted4[CAP];      // 16 KB
    __shared__ int hist[BS + 1];
    __shared__ int cursor[BS];

    const int b = blockIdx.x;
    const int t = threadIdx.x;
    const int s = b * CAP;
    const int cnt = bcur[b] - s;

    if (t < BS + 1) hist[t] = 0;
    __syncthreads();

    unsigned ek[8]; unsigned short ev[8];
    #pragma unroll
    for (int j = 0; j < 8; ++j) {
        int idx = t + j * 512;
        if (idx < cnt) {
            ek[j] = segk[s + idx];
            ev[j] = segv[s + idx];
            atomicAdd(&hist[ek[j] & 127], 1);
        }
    }
    __syncthreads();

    if (t == 0) {
        int run = 0;
        for (int i = 0; i < BS; ++i) { int c = hist[i]; hist[i] = run; run += c; }
        hist[BS] = run;
    }
    __syncthreads();

    if (t < BS) {
        cursor[t] = hist[t];
        offs[b * BS + t] = s + hist[t];
        rend[b * BS + t] = s + hist[t + 1];
    }
    __syncthreads();

    #pragma unroll
    for (int j = 0; j < 8; ++j) {
        int idx = t + j * 512;
        if (idx < cnt) {
            int pos = atomicAdd(&cursor[ek[j] & 127], 1);
            sorted4[pos] = ((ek[j] >> 7) << 16) | (unsigned)ev[j];
        }
    }
    __syncthreads();

    #pragma unroll
    for (int j = 0; j < 8; ++j) {
        int idx = t + j * 512;
        if (idx < cnt) segc[s + idx] = sorted4[idx];
    }
}

// ---------------- SpMM: 4 rows per wave (16-lane groups), 16-deep ------------
__global__ __launch_bounds__(256) void spmm_row_kernel(
    const int* __restrict__ offs, const int* __restrict__ rend,
    const unsigned* __restrict__ segc,
    const __hip_bfloat16* __restrict__ x,
    __hip_bfloat16* __restrict__ yb,      // bf16 out (pass 1)
    float* __restrict__ yf,               // fp32 out (final pass), or null
    const float* __restrict__ bias, int N)
{
    const int tid = threadIdx.x;
    const int lane = tid & 63;
    const int wave = tid >> 6;
    const int grp = lane >> 4;            // 0..3: row within wave
    const int l16 = lane & 15;            // channel group: 4*l16..4*l16+3

    int r = (blockIdx.x * 4 + wave) * 4 + grp;
    const bool rv = r < N;
    const int rc = rv ? r : N - 1;
    const int s = offs[rc];
    const int e = rv ? rend[rc] : s;      // empty range for OOB rows

    int m = e - s;
    m = max(m, __shfl_xor(m, 16));
    m = max(m, __shfl_xor(m, 32));
    const int iters = (m + 15) >> 4;

    const ushort* xp = (const ushort*)x + l16 * 4;

    float4 acc = {0.f, 0.f, 0.f, 0.f};
    for (int it = 0; it < iters; ++it) {
        const int base = s + it * 16;
        unsigned p[16];
        #pragma unroll
        for (int j = 0; j < 16; ++j) {
            int idx = base + j;
            p[j] = segc[idx < e ? idx : s];   // s is always a valid index
        }
        ushort4 xv[16];
        #pragma unroll
        for (int j = 0; j < 16; ++j)
            xv[j] = *(const ushort4*)(xp + (size_t)(p[j] >> 16) * OUT_CH);
        #pragma unroll
        for (int j = 0; j < 16; ++j) {
            int idx = base + j;
            float wv = (idx < e) ? __uint_as_float(p[j] << 16) : 0.f;
            acc.x = fmaf(wv, bf2f(xv[j].x), acc.x);
            acc.y = fmaf(wv, bf2f(xv[j].y), acc.y);
            acc.z = fmaf(wv, bf2f(xv[j].z), acc.z);
            acc.w = fmaf(wv, bf2f(xv[j].w), acc.w);
        }
    }

    if (rv) {
        if (yf) {
            float4 bv = *(const float4*)(bias + l16 * 4);
            float4 o;
            o.x = acc.x + bv.x; o.y = acc.y + bv.y;
            o.z = acc.z + bv.z; o.w = acc.w + bv.w;
            *(float4*)(yf + (size_t)r * OUT_CH + l16 * 4) = o;
        } else {
            ushort4 h;
            h.x = f2bf(acc.x); h.y = f2bf(acc.y);
            h.z = f2bf(acc.z); h.w = f2bf(acc.w);
            *(ushort4*)((ushort*)yb + (size_t)r * OUT_CH + l16 * 4) = h;
        }
    }
}

// ---------------- launch -----------------------------------------------------
static inline size_t align_up(size_t v) { return (v + 255) & ~(size_t)255; }

extern "C" void kernel_launch(void* const* d_in, const int* in_sizes, int n_in,
                              void* d_out, int out_size, void* d_ws, size_t ws_size,
                              hipStream_t stream)
{
    const int*   adj  = (const int*)d_in[0];    // [2,E]
    const float* vals = (const float*)d_in[1];  // [E]
    const float* feat = (const float*)d_in[2];  // [N,512]
    const float* Wm   = (const float*)d_in[3];  // [512,64]
    const float* bias = (const float*)d_in[4];  // [64]

    const int E = in_sizes[1];
    const int N = in_sizes[2] / IN_CH;
    const int* rows  = adj;
    const int* colsI = adj + E;

    char* w = (char*)d_ws;
    size_t o = 0;
    __hip_bfloat16* B0b = (__hip_bfloat16*)(w + o); o += align_up((size_t)N * OUT_CH * 2);
    __hip_bfloat16* Y1b = (__hip_bfloat16*)(w + o); o += align_up((size_t)N * OUT_CH * 2);
    __hip_bfloat16* Wf  = (__hip_bfloat16*)(w + o); o += align_up((size_t)IN_CH * OUT_CH * 2);
    int*            bcur = (int*)           (w + o); o += align_up(NB * sizeof(int));
    int*            offs = (int*)           (w + o); o += align_up((size_t)NB * BS * sizeof(int));
    int*            rend = (int*)           (w + o); o += align_up((size_t)NB * BS * sizeof(int));
    unsigned*       segk = (unsigned*)      (w + o); o += align_up((size_t)NB * CAP * sizeof(unsigned));
    unsigned short* segv = (unsigned short*)(w + o); o += align_up((size_t)NB * CAP * sizeof(unsigned short));
    unsigned*       segc = (unsigned*)      (w + o); o += align_up((size_t)NB * CAP * sizeof(unsigned));
    (void)ws_size; (void)n_in; (void)out_size;

    // 0. W -> bf16 B-fragments, bcur init
    prep_kernel<<<8, 512, 0, stream>>>(Wm, Wf, bcur);

    // 1. dense projection -> B0b (bf16)
    gemm_kernel<<<(N + 31) / 32, 128, 0, stream>>>(
        feat, (const bf16x8*)Wf, B0b, N);

    // 2. CSR build: fixed-capacity bucket scatter + per-bucket LDS sort
    bucket_scatter_kernel<<<(E + CHUNK - 1) / CHUNK, 512, 0, stream>>>(
        rows, colsI, vals, bcur, segk, segv, E);
    sort_kernel<<<NB, 512, 0, stream>>>(bcur, segk, segv, segc, offs, rend);

    // 3. two propagation rounds (bias fused into the last)
    const int rows_per_block = 16;
    spmm_row_kernel<<<(N + rows_per_block - 1) / rows_per_block, 256, 0, stream>>>(
        offs, rend, segc, B0b, Y1b, nullptr, nullptr, N);
    spmm_row_kernel<<<(N + rows_per_block - 1) / rows_per_block, 256, 0, stream>>>(
        offs, rend, segc, Y1b, nullptr, (float*)d_out, bias, N);
}

// Round 12
// 120.788 us; speedup vs baseline: 1.0437x; 1.0437x over previous
//
#include <hip/hip_runtime.h>
#include <hip/hip_bf16.h>

typedef __attribute__((ext_vector_type(8))) __bf16 bf16x8;
typedef __attribute__((ext_vector_type(4))) float f32x4;

#define IN_CH 512
#define OUT_CH 64
#define BS 98           // rows per bucket (rowres fits in 8 bits)
#define NB 512          // buckets; BS*NB = 50176 >= N
#define CHUNK 8192      // edges per scatter block (512 thr x 16)
#define CAP 4096        // fixed slots per bucket (mean 3125, +17 sigma)

__device__ inline unsigned short f2bf(float f) {
    __hip_bfloat16 h = __float2bfloat16(f);
    return __builtin_bit_cast(unsigned short, h);
}
__device__ inline float bf2f(unsigned short u) {
    return __uint_as_float(((unsigned)u) << 16);
}

// ---------------- prep: W -> MFMA B-fragments (bf16) + bcur init -------------
__global__ __launch_bounds__(512) void prep_kernel(
    const float* __restrict__ W, __hip_bfloat16* __restrict__ Wf,
    int* __restrict__ bcur)
{
    const int t = blockIdx.x * 512 + threadIdx.x;   // 0..4095
    if (t < NB) bcur[t] = t * CAP;
    const int ct = t >> 10;          // 0..3
    const int rem = t & 1023;
    const int ks = rem >> 6;         // 0..15
    const int l = rem & 63;          // lane
    const int col = ct * 16 + (l & 15);
    const int kb = ks * 32 + (l >> 4) * 8;
    __hip_bfloat16* dst = Wf + (size_t)t * 8;
    #pragma unroll
    for (int j = 0; j < 8; ++j)
        dst[j] = (__hip_bfloat16)W[(size_t)(kb + j) * OUT_CH + col];
}

// ---------------- GEMM: whole 32-row A-tile staged bf16, single barrier ------
__global__ __launch_bounds__(128) void gemm_kernel(
    const float* __restrict__ A, const bf16x8* __restrict__ wf,
    __hip_bfloat16* __restrict__ outb, int N)
{
    __shared__ __align__(16) char Abf[32 * 1024];   // 32 KB

    const int tid = threadIdx.x;
    const int row0 = blockIdx.x * 32;

    #pragma unroll 1
    for (int ob = 0; ob < 4; ++ob) {
        float4 v[8];
        #pragma unroll
        for (int j = 0; j < 8; ++j) {
            int f = (ob * 8 + j) * 128 + tid;
            int row = f >> 7, c4 = f & 127;
            int rg = row0 + row; rg = rg < N ? rg : N - 1;
            v[j] = *(const float4*)(A + (size_t)rg * IN_CH + c4 * 4);
        }
        #pragma unroll
        for (int j = 0; j < 8; ++j) {
            int f = (ob * 8 + j) * 128 + tid;
            int row = f >> 7, c4 = f & 127;
            int blk = c4 >> 1, half = c4 & 1;
            ushort4 h;
            h.x = f2bf(v[j].x); h.y = f2bf(v[j].y);
            h.z = f2bf(v[j].z); h.w = f2bf(v[j].w);
            *(ushort4*)(Abf + row * 1024 + ((blk ^ (row & 7)) << 4) + (half << 3)) = h;
        }
    }
    __syncthreads();

    const int lane = tid & 63;
    const int wave = tid >> 6;
    const int arow = wave * 16 + (lane & 15);
    const int kgb = lane >> 4;

    bf16x8 a[16];
    #pragma unroll
    for (int ks = 0; ks < 16; ++ks)
        a[ks] = *(const bf16x8*)(Abf + arow * 1024 +
                                 (((ks * 4 + kgb) ^ (arow & 7)) << 4));

    const int colb = lane & 15;
    const int rr = row0 + wave * 16 + (lane >> 4) * 4;
    #pragma unroll 1
    for (int ct = 0; ct < 4; ++ct) {
        bf16x8 w[16];
        #pragma unroll
        for (int ks = 0; ks < 16; ++ks) w[ks] = wf[(ct * 16 + ks) * 64 + lane];
        f32x4 acc = {0.f, 0.f, 0.f, 0.f};
        #pragma unroll
        for (int ks = 0; ks < 16; ++ks)
            acc = __builtin_amdgcn_mfma_f32_16x16x32_bf16(a[ks], w[ks], acc, 0, 0, 0);
        int col = ct * 16 + colb;
        #pragma unroll
        for (int i = 0; i < 4; ++i) {
            int r = rr + i;
            if (r < N)
                outb[(size_t)r * OUT_CH + col] = __float2bfloat16(acc[i]);
        }
    }
}

// ---------------- bucket scatter: 8192 edges/block, 16 consecutive/thread ----
__global__ __launch_bounds__(512) void bucket_scatter_kernel(
    const int* __restrict__ rows, const int* __restrict__ cols,
    const float* __restrict__ vals, int* __restrict__ bcur,
    int2* __restrict__ seg, int E)
{
    __shared__ int hist[NB];
    __shared__ int posBase[NB];
    const int tid = threadIdx.x;
    const int base = blockIdx.x * CHUNK + tid * 16;

    hist[tid] = 0;
    __syncthreads();

    int myb[16], mypack[16]; float myval[16];
    if (base + 16 <= E) {
        int4 r4[4], c4[4]; float4 v4[4];
        #pragma unroll
        for (int q = 0; q < 4; ++q) {
            r4[q] = *(const int4*)(rows + base + q * 4);
            c4[q] = *(const int4*)(cols + base + q * 4);
            v4[q] = *(const float4*)(vals + base + q * 4);
        }
        #pragma unroll
        for (int q = 0; q < 4; ++q) {
            int rr[4] = {r4[q].x, r4[q].y, r4[q].z, r4[q].w};
            int cc[4] = {c4[q].x, c4[q].y, c4[q].z, c4[q].w};
            float vv[4] = {v4[q].x, v4[q].y, v4[q].z, v4[q].w};
            #pragma unroll
            for (int u = 0; u < 4; ++u) {
                int j = q * 4 + u;
                int r = rr[u];
                int b = r / BS;
                myb[j] = b;
                mypack[j] = (cc[u] << 8) | (r - b * BS);
                myval[j] = vv[u];
                atomicAdd(&hist[b], 1);
            }
        }
    } else {
        #pragma unroll
        for (int j = 0; j < 16; ++j) {
            int e = base + j;
            myb[j] = -1;
            if (e < E) {
                int r = rows[e];
                int b = r / BS;
                myb[j] = b;
                mypack[j] = (cols[e] << 8) | (r - b * BS);
                myval[j] = vals[e];
                atomicAdd(&hist[b], 1);
            }
        }
    }
    __syncthreads();

    int h = hist[tid];
    if (h) posBase[tid] = atomicAdd(&bcur[tid], h);
    hist[tid] = 0;   // reuse as local cursor
    __syncthreads();

    #pragma unroll
    for (int j = 0; j < 16; ++j) {
        if (myb[j] >= 0) {
            int p = posBase[myb[j]] + atomicAdd(&hist[myb[j]], 1);
            int2 cv; cv.x = mypack[j]; cv.y = __float_as_int(myval[j]);
            seg[p] = cv;
        }
    }
}

// ---------------- per-bucket LDS sort -> 4B compact entries + offs/rend ------
// Output entry: (col << 16) | bf16(val)   (decode: val = asfloat(p<<16))
__global__ __launch_bounds__(512) void sort_kernel(
    const int* __restrict__ bcur, const int2* __restrict__ seg,
    unsigned* __restrict__ segc,
    int* __restrict__ offs, int* __restrict__ rend)
{
    __shared__ unsigned sorted4[CAP];      // 16 KB
    __shared__ int hist[BS + 1];
    __shared__ int cursor[BS];

    const int b = blockIdx.x;
    const int t = threadIdx.x;
    const int s = b * CAP;
    const int cnt = bcur[b] - s;

    if (t < BS + 1) hist[t] = 0;
    __syncthreads();

    int2 ed[8];
    #pragma unroll
    for (int j = 0; j < 8; ++j) {
        int idx = t + j * 512;
        if (idx < cnt) {
            ed[j] = seg[s + idx];
            atomicAdd(&hist[ed[j].x & 255], 1);
        }
    }
    __syncthreads();

    if (t == 0) {
        int run = 0;
        for (int i = 0; i < BS; ++i) { int c = hist[i]; hist[i] = run; run += c; }
        hist[BS] = run;
    }
    __syncthreads();

    if (t < BS) {
        cursor[t] = hist[t];
        offs[b * BS + t] = s + hist[t];
        rend[b * BS + t] = s + hist[t + 1];
    }
    __syncthreads();

    #pragma unroll
    for (int j = 0; j < 8; ++j) {
        int idx = t + j * 512;
        if (idx < cnt) {
            int pos = atomicAdd(&cursor[ed[j].x & 255], 1);
            unsigned col = ((unsigned)ed[j].x) >> 8;
            sorted4[pos] = (col << 16) | f2bf(__int_as_float(ed[j].y));
        }
    }
    __syncthreads();

    #pragma unroll
    for (int j = 0; j < 8; ++j) {
        int idx = t + j * 512;
        if (idx < cnt) segc[s + idx] = sorted4[idx];
    }
}

// ---------------- SpMM: 4 rows/wave (16-lane groups), 16-deep, pipelined -----
// Stage order per iter: gathers(p_cur) -> segc loads(p_next) -> FMAs(p_cur).
// p_next flies under the gather drain; gathers of iter i+1 issue right after
// FMAs of iter i.
__global__ __launch_bounds__(256) void spmm_row_kernel(
    const int* __restrict__ offs, const int* __restrict__ rend,
    const unsigned* __restrict__ segc,
    const __hip_bfloat16* __restrict__ x,
    __hip_bfloat16* __restrict__ yb,      // bf16 out (pass 1)
    float* __restrict__ yf,               // fp32 out (final pass), or null
    const float* __restrict__ bias, int N)
{
    const int tid = threadIdx.x;
    const int lane = tid & 63;
    const int wave = tid >> 6;
    const int grp = lane >> 4;            // 0..3: row within wave
    const int l16 = lane & 15;            // channel group: 4*l16..4*l16+3

    int r = (blockIdx.x * 4 + wave) * 4 + grp;
    const bool rv = r < N;
    const int rc = rv ? r : N - 1;
    const int s = offs[rc];
    const int e = rv ? rend[rc] : s;      // empty range for OOB rows

    int m = e - s;
    m = max(m, __shfl_xor(m, 16));
    m = max(m, __shfl_xor(m, 32));
    const int iters = (m + 15) >> 4;

    const ushort* xp = (const ushort*)x + l16 * 4;

    float4 acc = {0.f, 0.f, 0.f, 0.f};

    unsigned pc[16];
    #pragma unroll
    for (int j = 0; j < 16; ++j) {
        int idx = s + j;
        pc[j] = segc[idx < e ? idx : s];      // s always valid
    }

    int base = s;
    for (int it = 0; it < iters; ++it) {
        // 1. gathers for current entries (long pole — issue first)
        ushort4 xv[16];
        #pragma unroll
        for (int j = 0; j < 16; ++j)
            xv[j] = *(const ushort4*)(xp + (size_t)(pc[j] >> 16) * OUT_CH);

        // 2. next iteration's segc loads (independent; fly under the drain)
        unsigned pn[16];
        const int nbase = base + 16;
        const bool more = (it + 1 < iters);
        #pragma unroll
        for (int j = 0; j < 16; ++j) {
            int idx = nbase + j;
            pn[j] = segc[(more && idx < e) ? idx : s];
        }

        // 3. FMAs on current
        #pragma unroll
        for (int j = 0; j < 16; ++j) {
            int idx = base + j;
            float wv = (idx < e) ? __uint_as_float(pc[j] << 16) : 0.f;
            acc.x = fmaf(wv, bf2f(xv[j].x), acc.x);
            acc.y = fmaf(wv, bf2f(xv[j].y), acc.y);
            acc.z = fmaf(wv, bf2f(xv[j].z), acc.z);
            acc.w = fmaf(wv, bf2f(xv[j].w), acc.w);
        }
        #pragma unroll
        for (int j = 0; j < 16; ++j) pc[j] = pn[j];
        base = nbase;
    }

    if (rv) {
        if (yf) {
            float4 bv = *(const float4*)(bias + l16 * 4);
            float4 o;
            o.x = acc.x + bv.x; o.y = acc.y + bv.y;
            o.z = acc.z + bv.z; o.w = acc.w + bv.w;
            *(float4*)(yf + (size_t)r * OUT_CH + l16 * 4) = o;
        } else {
            ushort4 h;
            h.x = f2bf(acc.x); h.y = f2bf(acc.y);
            h.z = f2bf(acc.z); h.w = f2bf(acc.w);
            *(ushort4*)((ushort*)yb + (size_t)r * OUT_CH + l16 * 4) = h;
        }
    }
}

// ---------------- launch -----------------------------------------------------
static inline size_t align_up(size_t v) { return (v + 255) & ~(size_t)255; }

extern "C" void kernel_launch(void* const* d_in, const int* in_sizes, int n_in,
                              void* d_out, int out_size, void* d_ws, size_t ws_size,
                              hipStream_t stream)
{
    const int*   adj  = (const int*)d_in[0];    // [2,E]
    const float* vals = (const float*)d_in[1];  // [E]
    const float* feat = (const float*)d_in[2];  // [N,512]
    const float* Wm   = (const float*)d_in[3];  // [512,64]
    const float* bias = (const float*)d_in[4];  // [64]

    const int E = in_sizes[1];
    const int N = in_sizes[2] / IN_CH;
    const int* rows  = adj;
    const int* colsI = adj + E;

    char* w = (char*)d_ws;
    size_t o = 0;
    __hip_bfloat16* B0b = (__hip_bfloat16*)(w + o); o += align_up((size_t)N * OUT_CH * 2);
    __hip_bfloat16* Y1b = (__hip_bfloat16*)(w + o); o += align_up((size_t)N * OUT_CH * 2);
    __hip_bfloat16* Wf  = (__hip_bfloat16*)(w + o); o += align_up((size_t)IN_CH * OUT_CH * 2);
    int*      bcur = (int*)     (w + o); o += align_up(NB * sizeof(int));
    int*      offs = (int*)     (w + o); o += align_up((size_t)NB * BS * sizeof(int));
    int*      rend = (int*)     (w + o); o += align_up((size_t)NB * BS * sizeof(int));
    int2*     seg  = (int2*)    (w + o); o += align_up((size_t)NB * CAP * sizeof(int2));
    unsigned* segc = (unsigned*)(w + o); o += align_up((size_t)NB * CAP * sizeof(unsigned));
    (void)ws_size; (void)n_in; (void)out_size;

    // 0. W -> bf16 B-fragments, bcur init
    prep_kernel<<<8, 512, 0, stream>>>(Wm, Wf, bcur);

    // 1. dense projection -> B0b (bf16)
    gemm_kernel<<<(N + 31) / 32, 128, 0, stream>>>(
        feat, (const bf16x8*)Wf, B0b, N);

    // 2. CSR build: fixed-capacity bucket scatter + per-bucket LDS sort
    bucket_scatter_kernel<<<(E + CHUNK - 1) / CHUNK, 512, 0, stream>>>(
        rows, colsI, vals, bcur, seg, E);
    sort_kernel<<<NB, 512, 0, stream>>>(bcur, seg, segc, offs, rend);

    // 3. two propagation rounds (bias fused into the last)
    const int rows_per_block = 16;
    spmm_row_kernel<<<(N + rows_per_block - 1) / rows_per_block, 256, 0, stream>>>(
        offs, rend, segc, B0b, Y1b, nullptr, nullptr, N);
    spmm_row_kernel<<<(N + rows_per_block - 1) / rows_per_block, 256, 0, stream>>>(
        offs, rend, segc, Y1b, nullptr, (float*)d_out, bias, N);
}

// Round 13
// 113.429 us; speedup vs baseline: 1.1115x; 1.0649x over previous
//
#include <hip/hip_runtime.h>
#include <hip/hip_bf16.h>

typedef __attribute__((ext_vector_type(8))) __bf16 bf16x8;
typedef __attribute__((ext_vector_type(4))) float f32x4;

#define IN_CH 512
#define OUT_CH 64
#define BS 98           // rows per bucket (rowres fits in 8 bits)
#define NB 512          // buckets; BS*NB = 50176 >= N
#define CHUNK 8192      // edges per scatter block (512 thr x 16)
#define CAP 4096        // fixed slots per bucket (mean 3125, +17 sigma)

__device__ inline unsigned short f2bf(float f) {
    __hip_bfloat16 h = __float2bfloat16(f);
    return __builtin_bit_cast(unsigned short, h);
}
__device__ inline float bf2f(unsigned short u) {
    return __uint_as_float(((unsigned)u) << 16);
}

// ---------------- prep: W -> MFMA B-fragments (bf16) + bcur init -------------
__global__ __launch_bounds__(512) void prep_kernel(
    const float* __restrict__ W, __hip_bfloat16* __restrict__ Wf,
    int* __restrict__ bcur)
{
    const int t = blockIdx.x * 512 + threadIdx.x;   // 0..4095
    if (t < NB) bcur[t] = t * CAP;
    const int ct = t >> 10;          // 0..3
    const int rem = t & 1023;
    const int ks = rem >> 6;         // 0..15
    const int l = rem & 63;          // lane
    const int col = ct * 16 + (l & 15);
    const int kb = ks * 32 + (l >> 4) * 8;
    __hip_bfloat16* dst = Wf + (size_t)t * 8;
    #pragma unroll
    for (int j = 0; j < 8; ++j)
        dst[j] = (__hip_bfloat16)W[(size_t)(kb + j) * OUT_CH + col];
}

// ---------------- GEMM: 32-row A-tile staged bf16, pipelined staging ---------
__global__ __launch_bounds__(128) void gemm_kernel(
    const float* __restrict__ A, const bf16x8* __restrict__ wf,
    __hip_bfloat16* __restrict__ outb, int N)
{
    __shared__ __align__(16) char Abf[32 * 1024];   // 32 KB

    const int tid = threadIdx.x;
    const int row0 = blockIdx.x * 32;

    // staging: 32 float4/thread in 4 batches, software-pipelined (1 drain)
    float4 v[8], vn[8];
    #pragma unroll
    for (int j = 0; j < 8; ++j) {
        int f = j * 128 + tid;
        int row = f >> 7, c4 = f & 127;
        int rg = row0 + row; rg = rg < N ? rg : N - 1;
        v[j] = *(const float4*)(A + (size_t)rg * IN_CH + c4 * 4);
    }
    #pragma unroll 1
    for (int ob = 0; ob < 4; ++ob) {
        if (ob < 3) {
            #pragma unroll
            for (int j = 0; j < 8; ++j) {
                int f = ((ob + 1) * 8 + j) * 128 + tid;
                int row = f >> 7, c4 = f & 127;
                int rg = row0 + row; rg = rg < N ? rg : N - 1;
                vn[j] = *(const float4*)(A + (size_t)rg * IN_CH + c4 * 4);
            }
        }
        #pragma unroll
        for (int j = 0; j < 8; ++j) {
            int f = (ob * 8 + j) * 128 + tid;
            int row = f >> 7, c4 = f & 127;
            int blk = c4 >> 1, half = c4 & 1;
            ushort4 h;
            h.x = f2bf(v[j].x); h.y = f2bf(v[j].y);
            h.z = f2bf(v[j].z); h.w = f2bf(v[j].w);
            *(ushort4*)(Abf + row * 1024 + ((blk ^ (row & 7)) << 4) + (half << 3)) = h;
        }
        #pragma unroll
        for (int j = 0; j < 8; ++j) v[j] = vn[j];
    }
    __syncthreads();

    const int lane = tid & 63;
    const int wave = tid >> 6;
    const int arow = wave * 16 + (lane & 15);
    const int kgb = lane >> 4;

    bf16x8 a[16];
    #pragma unroll
    for (int ks = 0; ks < 16; ++ks)
        a[ks] = *(const bf16x8*)(Abf + arow * 1024 +
                                 (((ks * 4 + kgb) ^ (arow & 7)) << 4));

    const int colb = lane & 15;
    const int rr = row0 + wave * 16 + (lane >> 4) * 4;
    #pragma unroll 1
    for (int ct = 0; ct < 4; ++ct) {
        bf16x8 w[16];
        #pragma unroll
        for (int ks = 0; ks < 16; ++ks) w[ks] = wf[(ct * 16 + ks) * 64 + lane];
        f32x4 acc = {0.f, 0.f, 0.f, 0.f};
        #pragma unroll
        for (int ks = 0; ks < 16; ++ks)
            acc = __builtin_amdgcn_mfma_f32_16x16x32_bf16(a[ks], w[ks], acc, 0, 0, 0);
        int col = ct * 16 + colb;
        #pragma unroll
        for (int i = 0; i < 4; ++i) {
            int r = rr + i;
            if (r < N)
                outb[(size_t)r * OUT_CH + col] = __float2bfloat16(acc[i]);
        }
    }
}

// ---------------- bucket scatter: 8192 edges/block, 16 consecutive/thread ----
__global__ __launch_bounds__(512) void bucket_scatter_kernel(
    const int* __restrict__ rows, const int* __restrict__ cols,
    const float* __restrict__ vals, int* __restrict__ bcur,
    int2* __restrict__ seg, int E)
{
    __shared__ int hist[NB];
    __shared__ int posBase[NB];
    const int tid = threadIdx.x;
    const int base = blockIdx.x * CHUNK + tid * 16;

    hist[tid] = 0;
    __syncthreads();

    int myb[16], mypack[16]; float myval[16];
    if (base + 16 <= E) {
        int4 r4[4], c4[4]; float4 v4[4];
        #pragma unroll
        for (int q = 0; q < 4; ++q) {
            r4[q] = *(const int4*)(rows + base + q * 4);
            c4[q] = *(const int4*)(cols + base + q * 4);
            v4[q] = *(const float4*)(vals + base + q * 4);
        }
        #pragma unroll
        for (int q = 0; q < 4; ++q) {
            int rr[4] = {r4[q].x, r4[q].y, r4[q].z, r4[q].w};
            int cc[4] = {c4[q].x, c4[q].y, c4[q].z, c4[q].w};
            float vv[4] = {v4[q].x, v4[q].y, v4[q].z, v4[q].w};
            #pragma unroll
            for (int u = 0; u < 4; ++u) {
                int j = q * 4 + u;
                int r = rr[u];
                int b = r / BS;
                myb[j] = b;
                mypack[j] = (cc[u] << 8) | (r - b * BS);
                myval[j] = vv[u];
                atomicAdd(&hist[b], 1);
            }
        }
    } else {
        #pragma unroll
        for (int j = 0; j < 16; ++j) {
            int e = base + j;
            myb[j] = -1;
            if (e < E) {
                int r = rows[e];
                int b = r / BS;
                myb[j] = b;
                mypack[j] = (cols[e] << 8) | (r - b * BS);
                myval[j] = vals[e];
                atomicAdd(&hist[b], 1);
            }
        }
    }
    __syncthreads();

    int h = hist[tid];
    if (h) posBase[tid] = atomicAdd(&bcur[tid], h);
    hist[tid] = 0;   // reuse as local cursor
    __syncthreads();

    #pragma unroll
    for (int j = 0; j < 16; ++j) {
        if (myb[j] >= 0) {
            int p = posBase[myb[j]] + atomicAdd(&hist[myb[j]], 1);
            int2 cv; cv.x = mypack[j]; cv.y = __float_as_int(myval[j]);
            seg[p] = cv;
        }
    }
}

// ---------------- fused: per-bucket sort + pass-1 SpMM from LDS --------------
// Sorts bucket b into LDS, writes segc/offs/rend for pass 2, then computes
// y1 rows of this bucket reading entries straight from LDS.
__global__ __launch_bounds__(512) void sortspmm_kernel(
    const int* __restrict__ bcur, const int2* __restrict__ seg,
    unsigned* __restrict__ segc,
    int* __restrict__ offs, int* __restrict__ rend,
    const __hip_bfloat16* __restrict__ x,
    __hip_bfloat16* __restrict__ y1, int N)
{
    __shared__ unsigned sorted4[CAP];      // 16 KB
    __shared__ int hist[BS + 1];
    __shared__ int cursor[BS];

    const int b = blockIdx.x;
    const int t = threadIdx.x;
    const int s = b * CAP;
    const int cnt = bcur[b] - s;

    if (t < BS + 1) hist[t] = 0;
    __syncthreads();

    int2 ed[8];
    #pragma unroll
    for (int j = 0; j < 8; ++j) {
        int idx = t + j * 512;
        if (idx < cnt) {
            ed[j] = seg[s + idx];
            atomicAdd(&hist[ed[j].x & 255], 1);
        }
    }
    __syncthreads();

    if (t == 0) {
        int run = 0;
        for (int i = 0; i < BS; ++i) { int c = hist[i]; hist[i] = run; run += c; }
        hist[BS] = run;
    }
    __syncthreads();

    if (t < BS) {
        cursor[t] = hist[t];
        offs[b * BS + t] = s + hist[t];
        rend[b * BS + t] = s + hist[t + 1];
    }
    __syncthreads();

    #pragma unroll
    for (int j = 0; j < 8; ++j) {
        int idx = t + j * 512;
        if (idx < cnt) {
            int pos = atomicAdd(&cursor[ed[j].x & 255], 1);
            unsigned col = ((unsigned)ed[j].x) >> 8;
            sorted4[pos] = (col << 16) | f2bf(__int_as_float(ed[j].y));
        }
    }
    __syncthreads();

    // writeback for pass 2 (stores overlap the compute below)
    #pragma unroll
    for (int j = 0; j < 8; ++j) {
        int idx = t + j * 512;
        if (idx < cnt) segc[s + idx] = sorted4[idx];
    }

    // ---- pass-1 SpMM for this bucket's rows, entries from LDS ----
    const int lane = t & 63;
    const int wave = t >> 6;              // 0..7
    const int grp = lane >> 4;            // row within wave
    const int l16 = lane & 15;
    const ushort* xp = (const ushort*)x + l16 * 4;

    #pragma unroll 1
    for (int sweep = 0; sweep < 4; ++sweep) {
        int rr = sweep * 32 + wave * 4 + grp;   // row-in-bucket (0..127)
        int rrc = rr < BS ? rr : BS - 1;
        int rs = hist[rrc];
        int re = hist[rrc + 1];
        int gr = b * BS + rr;
        if (rr >= BS || gr >= N) re = rs;       // skip invalid rows

        float4 acc = {0.f, 0.f, 0.f, 0.f};
        for (int i0 = rs; i0 < re; i0 += 16) {
            unsigned p[16];
            #pragma unroll
            for (int j = 0; j < 16; ++j) {
                int idx = i0 + j;
                p[j] = sorted4[idx < re ? idx : rs];
            }
            ushort4 xv[16];
            #pragma unroll
            for (int j = 0; j < 16; ++j)
                xv[j] = *(const ushort4*)(xp + (size_t)(p[j] >> 16) * OUT_CH);
            #pragma unroll
            for (int j = 0; j < 16; ++j) {
                float wv = (i0 + j < re) ? __uint_as_float(p[j] << 16) : 0.f;
                acc.x = fmaf(wv, bf2f(xv[j].x), acc.x);
                acc.y = fmaf(wv, bf2f(xv[j].y), acc.y);
                acc.z = fmaf(wv, bf2f(xv[j].z), acc.z);
                acc.w = fmaf(wv, bf2f(xv[j].w), acc.w);
            }
        }
        if (rr < BS && gr < N) {
            ushort4 h;
            h.x = f2bf(acc.x); h.y = f2bf(acc.y);
            h.z = f2bf(acc.z); h.w = f2bf(acc.w);
            *(ushort4*)((ushort*)y1 + (size_t)gr * OUT_CH + l16 * 4) = h;
        }
    }
}

// ---------------- SpMM pass 2: 4 rows/wave (16-lane groups), 16-deep ---------
__global__ __launch_bounds__(256) void spmm_row_kernel(
    const int* __restrict__ offs, const int* __restrict__ rend,
    const unsigned* __restrict__ segc,
    const __hip_bfloat16* __restrict__ x,
    float* __restrict__ yf, const float* __restrict__ bias, int N)
{
    const int tid = threadIdx.x;
    const int lane = tid & 63;
    const int wave = tid >> 6;
    const int grp = lane >> 4;
    const int l16 = lane & 15;

    int r = (blockIdx.x * 4 + wave) * 4 + grp;
    const bool rv = r < N;
    const int rc = rv ? r : N - 1;
    const int s = offs[rc];
    const int e = rv ? rend[rc] : s;

    int m = e - s;
    m = max(m, __shfl_xor(m, 16));
    m = max(m, __shfl_xor(m, 32));
    const int iters = (m + 15) >> 4;

    const ushort* xp = (const ushort*)x + l16 * 4;

    float4 acc = {0.f, 0.f, 0.f, 0.f};
    for (int it = 0; it < iters; ++it) {
        const int base = s + it * 16;
        unsigned p[16];
        #pragma unroll
        for (int j = 0; j < 16; ++j) {
            int idx = base + j;
            p[j] = segc[idx < e ? idx : s];
        }
        ushort4 xv[16];
        #pragma unroll
        for (int j = 0; j < 16; ++j)
            xv[j] = *(const ushort4*)(xp + (size_t)(p[j] >> 16) * OUT_CH);
        #pragma unroll
        for (int j = 0; j < 16; ++j) {
            int idx = base + j;
            float wv = (idx < e) ? __uint_as_float(p[j] << 16) : 0.f;
            acc.x = fmaf(wv, bf2f(xv[j].x), acc.x);
            acc.y = fmaf(wv, bf2f(xv[j].y), acc.y);
            acc.z = fmaf(wv, bf2f(xv[j].z), acc.z);
            acc.w = fmaf(wv, bf2f(xv[j].w), acc.w);
        }
    }

    if (rv) {
        float4 bv = *(const float4*)(bias + l16 * 4);
        float4 o;
        o.x = acc.x + bv.x; o.y = acc.y + bv.y;
        o.z = acc.z + bv.z; o.w = acc.w + bv.w;
        *(float4*)(yf + (size_t)r * OUT_CH + l16 * 4) = o;
    }
}

// ---------------- launch -----------------------------------------------------
static inline size_t align_up(size_t v) { return (v + 255) & ~(size_t)255; }

extern "C" void kernel_launch(void* const* d_in, const int* in_sizes, int n_in,
                              void* d_out, int out_size, void* d_ws, size_t ws_size,
                              hipStream_t stream)
{
    const int*   adj  = (const int*)d_in[0];    // [2,E]
    const float* vals = (const float*)d_in[1];  // [E]
    const float* feat = (const float*)d_in[2];  // [N,512]
    const float* Wm   = (const float*)d_in[3];  // [512,64]
    const float* bias = (const float*)d_in[4];  // [64]

    const int E = in_sizes[1];
    const int N = in_sizes[2] / IN_CH;
    const int* rows  = adj;
    const int* colsI = adj + E;

    char* w = (char*)d_ws;
    size_t o = 0;
    __hip_bfloat16* B0b = (__hip_bfloat16*)(w + o); o += align_up((size_t)N * OUT_CH * 2);
    __hip_bfloat16* Y1b = (__hip_bfloat16*)(w + o); o += align_up((size_t)N * OUT_CH * 2);
    __hip_bfloat16* Wf  = (__hip_bfloat16*)(w + o); o += align_up((size_t)IN_CH * OUT_CH * 2);
    int*      bcur = (int*)     (w + o); o += align_up(NB * sizeof(int));
    int*      offs = (int*)     (w + o); o += align_up((size_t)NB * BS * sizeof(int));
    int*      rend = (int*)     (w + o); o += align_up((size_t)NB * BS * sizeof(int));
    int2*     seg  = (int2*)    (w + o); o += align_up((size_t)NB * CAP * sizeof(int2));
    unsigned* segc = (unsigned*)(w + o); o += align_up((size_t)NB * CAP * sizeof(unsigned));
    (void)ws_size; (void)n_in; (void)out_size;

    // 0. W -> bf16 B-fragments, bcur init
    prep_kernel<<<8, 512, 0, stream>>>(Wm, Wf, bcur);

    // 1. dense projection -> B0b (bf16)
    gemm_kernel<<<(N + 31) / 32, 128, 0, stream>>>(
        feat, (const bf16x8*)Wf, B0b, N);

    // 2. bucket scatter
    bucket_scatter_kernel<<<(E + CHUNK - 1) / CHUNK, 512, 0, stream>>>(
        rows, colsI, vals, bcur, seg, E);

    // 3. fused per-bucket sort + pass-1 SpMM (B0b -> Y1b)
    sortspmm_kernel<<<NB, 512, 0, stream>>>(
        bcur, seg, segc, offs, rend, B0b, Y1b, N);

    // 4. pass-2 SpMM (+bias) -> d_out
    spmm_row_kernel<<<(N + 15) / 16, 256, 0, stream>>>(
        offs, rend, segc, Y1b, (float*)d_out, bias, N);
}

// Round 14
// 113.407 us; speedup vs baseline: 1.1117x; 1.0002x over previous
//
#include <hip/hip_runtime.h>
#include <hip/hip_bf16.h>

typedef __attribute__((ext_vector_type(8))) __bf16 bf16x8;
typedef __attribute__((ext_vector_type(4))) float f32x4;

#define IN_CH 512
#define OUT_CH 64
#define BS 98           // rows per bucket (rowres fits in 8 bits)
#define NB 512          // buckets; BS*NB = 50176 >= N
#define CHUNK 8192      // edges per scatter block (512 thr x 16)
#define CAP 4096        // fixed slots per bucket (mean 3125, +17 sigma)

__device__ inline unsigned short f2bf(float f) {
    __hip_bfloat16 h = __float2bfloat16(f);
    return __builtin_bit_cast(unsigned short, h);
}
__device__ inline float bf2f(unsigned short u) {
    return __uint_as_float(((unsigned)u) << 16);
}

// ---------------- prep: W -> MFMA B-fragments (bf16) + bcur init -------------
__global__ __launch_bounds__(512) void prep_kernel(
    const float* __restrict__ W, __hip_bfloat16* __restrict__ Wf,
    int* __restrict__ bcur)
{
    const int t = blockIdx.x * 512 + threadIdx.x;   // 0..4095
    if (t < NB) bcur[t] = t * CAP;
    const int ct = t >> 10;          // 0..3
    const int rem = t & 1023;
    const int ks = rem >> 6;         // 0..15
    const int l = rem & 63;          // lane
    const int col = ct * 16 + (l & 15);
    const int kb = ks * 32 + (l >> 4) * 8;
    __hip_bfloat16* dst = Wf + (size_t)t * 8;
    #pragma unroll
    for (int j = 0; j < 8; ++j)
        dst[j] = (__hip_bfloat16)W[(size_t)(kb + j) * OUT_CH + col];
}

// ---------------- GEMM: 32-row A-tile staged bf16, pipelined staging ---------
__global__ __launch_bounds__(128) void gemm_kernel(
    const float* __restrict__ A, const bf16x8* __restrict__ wf,
    __hip_bfloat16* __restrict__ outb, int N)
{
    __shared__ __align__(16) char Abf[32 * 1024];   // 32 KB

    const int tid = threadIdx.x;
    const int row0 = blockIdx.x * 32;

    float4 v[8], vn[8];
    #pragma unroll
    for (int j = 0; j < 8; ++j) {
        int f = j * 128 + tid;
        int row = f >> 7, c4 = f & 127;
        int rg = row0 + row; rg = rg < N ? rg : N - 1;
        v[j] = *(const float4*)(A + (size_t)rg * IN_CH + c4 * 4);
    }
    #pragma unroll 1
    for (int ob = 0; ob < 4; ++ob) {
        if (ob < 3) {
            #pragma unroll
            for (int j = 0; j < 8; ++j) {
                int f = ((ob + 1) * 8 + j) * 128 + tid;
                int row = f >> 7, c4 = f & 127;
                int rg = row0 + row; rg = rg < N ? rg : N - 1;
                vn[j] = *(const float4*)(A + (size_t)rg * IN_CH + c4 * 4);
            }
        }
        #pragma unroll
        for (int j = 0; j < 8; ++j) {
            int f = (ob * 8 + j) * 128 + tid;
            int row = f >> 7, c4 = f & 127;
            int blk = c4 >> 1, half = c4 & 1;
            ushort4 h;
            h.x = f2bf(v[j].x); h.y = f2bf(v[j].y);
            h.z = f2bf(v[j].z); h.w = f2bf(v[j].w);
            *(ushort4*)(Abf + row * 1024 + ((blk ^ (row & 7)) << 4) + (half << 3)) = h;
        }
        #pragma unroll
        for (int j = 0; j < 8; ++j) v[j] = vn[j];
    }
    __syncthreads();

    const int lane = tid & 63;
    const int wave = tid >> 6;
    const int arow = wave * 16 + (lane & 15);
    const int kgb = lane >> 4;

    bf16x8 a[16];
    #pragma unroll
    for (int ks = 0; ks < 16; ++ks)
        a[ks] = *(const bf16x8*)(Abf + arow * 1024 +
                                 (((ks * 4 + kgb) ^ (arow & 7)) << 4));

    const int colb = lane & 15;
    const int rr = row0 + wave * 16 + (lane >> 4) * 4;
    #pragma unroll 1
    for (int ct = 0; ct < 4; ++ct) {
        bf16x8 w[16];
        #pragma unroll
        for (int ks = 0; ks < 16; ++ks) w[ks] = wf[(ct * 16 + ks) * 64 + lane];
        f32x4 acc = {0.f, 0.f, 0.f, 0.f};
        #pragma unroll
        for (int ks = 0; ks < 16; ++ks)
            acc = __builtin_amdgcn_mfma_f32_16x16x32_bf16(a[ks], w[ks], acc, 0, 0, 0);
        int col = ct * 16 + colb;
        #pragma unroll
        for (int i = 0; i < 4; ++i) {
            int r = rr + i;
            if (r < N)
                outb[(size_t)r * OUT_CH + col] = __float2bfloat16(acc[i]);
        }
    }
}

// ---------------- bucket scatter: local counting sort + coalesced writeback --
// Writes 4B segc entries (col<<16 | bf16val) + 1B segr (rowres), grouped by
// bucket, fully coalesced within runs. No atomic->store dependency chains.
__global__ __launch_bounds__(512) void bucket_scatter_kernel(
    const int* __restrict__ rows, const int* __restrict__ cols,
    const float* __restrict__ vals, int* __restrict__ bcur,
    unsigned* __restrict__ segc, unsigned char* __restrict__ segr, int E)
{
    __shared__ unsigned      c_lds[CHUNK];        // 32 KB
    __shared__ unsigned char r_lds[CHUNK];        // 8 KB
    __shared__ unsigned short b_lds[CHUNK];       // 16 KB
    __shared__ int hist[NB];                      // 2 KB
    __shared__ int scn[NB];                       // 2 KB
    __shared__ int lbase[NB];                     // 2 KB
    __shared__ int runBase[NB];                   // 2 KB

    const int tid = threadIdx.x;
    const int c0 = blockIdx.x * CHUNK;
    const int cnt = min(CHUNK, E - c0);
    const int base = c0 + tid * 16;

    hist[tid] = 0;
    __syncthreads();

    int myb[16]; unsigned myc[16]; unsigned char myr[16];
    int nmine = 0;
    if (base + 16 <= E) {
        nmine = 16;
        int4 r4[4], c4[4]; float4 v4[4];
        #pragma unroll
        for (int q = 0; q < 4; ++q) {
            r4[q] = *(const int4*)(rows + base + q * 4);
            c4[q] = *(const int4*)(cols + base + q * 4);
            v4[q] = *(const float4*)(vals + base + q * 4);
        }
        #pragma unroll
        for (int q = 0; q < 4; ++q) {
            int rr[4] = {r4[q].x, r4[q].y, r4[q].z, r4[q].w};
            int cc[4] = {c4[q].x, c4[q].y, c4[q].z, c4[q].w};
            float vv[4] = {v4[q].x, v4[q].y, v4[q].z, v4[q].w};
            #pragma unroll
            for (int u = 0; u < 4; ++u) {
                int j = q * 4 + u;
                int r = rr[u];
                int b = r / BS;
                myb[j] = b;
                myr[j] = (unsigned char)(r - b * BS);
                myc[j] = ((unsigned)cc[u] << 16) | f2bf(vv[u]);
                atomicAdd(&hist[b], 1);
            }
        }
    } else {
        #pragma unroll 1
        for (int j = 0; j < 16; ++j) {
            int e = base + j;
            if (e < E) {
                int r = rows[e];
                int b = r / BS;
                myb[j] = b;
                myr[j] = (unsigned char)(r - b * BS);
                myc[j] = ((unsigned)cols[e] << 16) | f2bf(vals[e]);
                atomicAdd(&hist[b], 1);
                nmine = j + 1;
            }
        }
    }
    __syncthreads();

    // block-wide exclusive scan of hist -> lbase; reserve global runs
    {
        int h = hist[tid];
        scn[tid] = h;
        __syncthreads();
        for (int ofs = 1; ofs < NB; ofs <<= 1) {
            int u = 0;
            if (tid >= ofs) u = scn[tid - ofs];
            __syncthreads();
            if (tid >= ofs) scn[tid] += u;
            __syncthreads();
        }
        int excl = scn[tid] - h;
        lbase[tid] = excl;
        hist[tid] = excl;                      // reuse as local cursor
        runBase[tid] = h ? atomicAdd(&bcur[tid], h) : 0;
    }
    __syncthreads();

    // scatter into LDS (sorted by bucket)
    #pragma unroll 1
    for (int j = 0; j < nmine; ++j) {
        int pos = atomicAdd(&hist[myb[j]], 1);
        c_lds[pos] = myc[j];
        r_lds[pos] = myr[j];
        b_lds[pos] = (unsigned short)myb[j];
    }
    __syncthreads();

    // coalesced writeback in LDS order
    for (int idx = tid; idx < cnt; idx += 512) {
        int b = b_lds[idx];
        int gpos = runBase[b] + (idx - lbase[b]);
        segc[gpos] = c_lds[idx];
        segr[gpos] = r_lds[idx];
    }
}

// ---------------- fused: per-bucket sort (in place) + pass-1 SpMM ------------
__global__ __launch_bounds__(512) void sortspmm_kernel(
    const int* __restrict__ bcur,
    unsigned* __restrict__ segc, const unsigned char* __restrict__ segr,
    int* __restrict__ offs, int* __restrict__ rend,
    const __hip_bfloat16* __restrict__ x,
    __hip_bfloat16* __restrict__ y1, int N)
{
    __shared__ unsigned sorted4[CAP];      // 16 KB
    __shared__ int hist[BS + 1];
    __shared__ int cursor[BS];

    const int b = blockIdx.x;
    const int t = threadIdx.x;
    const int s = b * CAP;
    const int cnt = bcur[b] - s;

    if (t < BS + 1) hist[t] = 0;
    __syncthreads();

    unsigned ek[8]; unsigned char er[8];
    #pragma unroll
    for (int j = 0; j < 8; ++j) {
        int idx = t + j * 512;
        if (idx < cnt) {
            ek[j] = segc[s + idx];
            er[j] = segr[s + idx];
            atomicAdd(&hist[er[j]], 1);
        }
    }
    __syncthreads();

    if (t == 0) {
        int run = 0;
        for (int i = 0; i < BS; ++i) { int c = hist[i]; hist[i] = run; run += c; }
        hist[BS] = run;
    }
    __syncthreads();

    if (t < BS) {
        cursor[t] = hist[t];
        offs[b * BS + t] = s + hist[t];
        rend[b * BS + t] = s + hist[t + 1];
    }
    __syncthreads();

    #pragma unroll
    for (int j = 0; j < 8; ++j) {
        int idx = t + j * 512;
        if (idx < cnt) {
            int pos = atomicAdd(&cursor[er[j]], 1);
            sorted4[pos] = ek[j];
        }
    }
    __syncthreads();

    // writeback sorted entries (in place; inputs already register-cached)
    #pragma unroll
    for (int j = 0; j < 8; ++j) {
        int idx = t + j * 512;
        if (idx < cnt) segc[s + idx] = sorted4[idx];
    }

    // ---- pass-1 SpMM for this bucket's rows, entries from LDS ----
    const int lane = t & 63;
    const int wave = t >> 6;              // 0..7
    const int grp = lane >> 4;            // row within wave
    const int l16 = lane & 15;
    const ushort* xp = (const ushort*)x + l16 * 4;

    #pragma unroll 1
    for (int sweep = 0; sweep < 4; ++sweep) {
        int rr = sweep * 32 + wave * 4 + grp;   // row-in-bucket (0..127)
        int rrc = rr < BS ? rr : BS - 1;
        int rs = hist[rrc];
        int re = hist[rrc + 1];
        int gr = b * BS + rr;
        if (rr >= BS || gr >= N) re = rs;       // skip invalid rows

        float4 acc = {0.f, 0.f, 0.f, 0.f};
        for (int i0 = rs; i0 < re; i0 += 16) {
            unsigned p[16];
            #pragma unroll
            for (int j = 0; j < 16; ++j) {
                int idx = i0 + j;
                p[j] = sorted4[idx < re ? idx : rs];
            }
            ushort4 xv[16];
            #pragma unroll
            for (int j = 0; j < 16; ++j)
                xv[j] = *(const ushort4*)(xp + (size_t)(p[j] >> 16) * OUT_CH);
            #pragma unroll
            for (int j = 0; j < 16; ++j) {
                float wv = (i0 + j < re) ? __uint_as_float(p[j] << 16) : 0.f;
                acc.x = fmaf(wv, bf2f(xv[j].x), acc.x);
                acc.y = fmaf(wv, bf2f(xv[j].y), acc.y);
                acc.z = fmaf(wv, bf2f(xv[j].z), acc.z);
                acc.w = fmaf(wv, bf2f(xv[j].w), acc.w);
            }
        }
        if (rr < BS && gr < N) {
            ushort4 h;
            h.x = f2bf(acc.x); h.y = f2bf(acc.y);
            h.z = f2bf(acc.z); h.w = f2bf(acc.w);
            *(ushort4*)((ushort*)y1 + (size_t)gr * OUT_CH + l16 * 4) = h;
        }
    }
}

// ---------------- SpMM pass 2: 4 rows/wave (16-lane groups), 16-deep ---------
__global__ __launch_bounds__(256) void spmm_row_kernel(
    const int* __restrict__ offs, const int* __restrict__ rend,
    const unsigned* __restrict__ segc,
    const __hip_bfloat16* __restrict__ x,
    float* __restrict__ yf, const float* __restrict__ bias, int N)
{
    const int tid = threadIdx.x;
    const int lane = tid & 63;
    const int wave = tid >> 6;
    const int grp = lane >> 4;
    const int l16 = lane & 15;

    int r = (blockIdx.x * 4 + wave) * 4 + grp;
    const bool rv = r < N;
    const int rc = rv ? r : N - 1;
    const int s = offs[rc];
    const int e = rv ? rend[rc] : s;

    int m = e - s;
    m = max(m, __shfl_xor(m, 16));
    m = max(m, __shfl_xor(m, 32));
    const int iters = (m + 15) >> 4;

    const ushort* xp = (const ushort*)x + l16 * 4;

    float4 acc = {0.f, 0.f, 0.f, 0.f};
    for (int it = 0; it < iters; ++it) {
        const int base = s + it * 16;
        unsigned p[16];
        #pragma unroll
        for (int j = 0; j < 16; ++j) {
            int idx = base + j;
            p[j] = segc[idx < e ? idx : s];
        }
        ushort4 xv[16];
        #pragma unroll
        for (int j = 0; j < 16; ++j)
            xv[j] = *(const ushort4*)(xp + (size_t)(p[j] >> 16) * OUT_CH);
        #pragma unroll
        for (int j = 0; j < 16; ++j) {
            int idx = base + j;
            float wv = (idx < e) ? __uint_as_float(p[j] << 16) : 0.f;
            acc.x = fmaf(wv, bf2f(xv[j].x), acc.x);
            acc.y = fmaf(wv, bf2f(xv[j].y), acc.y);
            acc.z = fmaf(wv, bf2f(xv[j].z), acc.z);
            acc.w = fmaf(wv, bf2f(xv[j].w), acc.w);
        }
    }

    if (rv) {
        float4 bv = *(const float4*)(bias + l16 * 4);
        float4 o;
        o.x = acc.x + bv.x; o.y = acc.y + bv.y;
        o.z = acc.z + bv.z; o.w = acc.w + bv.w;
        *(float4*)(yf + (size_t)r * OUT_CH + l16 * 4) = o;
    }
}

// ---------------- launch -----------------------------------------------------
static inline size_t align_up(size_t v) { return (v + 255) & ~(size_t)255; }

extern "C" void kernel_launch(void* const* d_in, const int* in_sizes, int n_in,
                              void* d_out, int out_size, void* d_ws, size_t ws_size,
                              hipStream_t stream)
{
    const int*   adj  = (const int*)d_in[0];    // [2,E]
    const float* vals = (const float*)d_in[1];  // [E]
    const float* feat = (const float*)d_in[2];  // [N,512]
    const float* Wm   = (const float*)d_in[3];  // [512,64]
    const float* bias = (const float*)d_in[4];  // [64]

    const int E = in_sizes[1];
    const int N = in_sizes[2] / IN_CH;
    const int* rows  = adj;
    const int* colsI = adj + E;

    char* w = (char*)d_ws;
    size_t o = 0;
    __hip_bfloat16* B0b = (__hip_bfloat16*)(w + o); o += align_up((size_t)N * OUT_CH * 2);
    __hip_bfloat16* Y1b = (__hip_bfloat16*)(w + o); o += align_up((size_t)N * OUT_CH * 2);
    __hip_bfloat16* Wf  = (__hip_bfloat16*)(w + o); o += align_up((size_t)IN_CH * OUT_CH * 2);
    int*           bcur = (int*)          (w + o); o += align_up(NB * sizeof(int));
    int*           offs = (int*)          (w + o); o += align_up((size_t)NB * BS * sizeof(int));
    int*           rend = (int*)          (w + o); o += align_up((size_t)NB * BS * sizeof(int));
    unsigned*      segc = (unsigned*)     (w + o); o += align_up((size_t)NB * CAP * sizeof(unsigned));
    unsigned char* segr = (unsigned char*)(w + o); o += align_up((size_t)NB * CAP);
    (void)ws_size; (void)n_in; (void)out_size;

    // 0. W -> bf16 B-fragments, bcur init
    prep_kernel<<<8, 512, 0, stream>>>(Wm, Wf, bcur);

    // 1. dense projection -> B0b (bf16)
    gemm_kernel<<<(N + 31) / 32, 128, 0, stream>>>(
        feat, (const bf16x8*)Wf, B0b, N);

    // 2. bucket scatter (local counting sort, coalesced writes)
    bucket_scatter_kernel<<<(E + CHUNK - 1) / CHUNK, 512, 0, stream>>>(
        rows, colsI, vals, bcur, segc, segr, E);

    // 3. fused per-bucket sort + pass-1 SpMM (B0b -> Y1b)
    sortspmm_kernel<<<NB, 512, 0, stream>>>(
        bcur, segc, segr, offs, rend, B0b, Y1b, N);

    // 4. pass-2 SpMM (+bias) -> d_out
    spmm_row_kernel<<<(N + 15) / 16, 256, 0, stream>>>(
        offs, rend, segc, Y1b, (float*)d_out, bias, N);
}

// Round 15
// 100.902 us; speedup vs baseline: 1.2495x; 1.1239x over previous
//
#include <hip/hip_runtime.h>
#include <hip/hip_bf16.h>

typedef __attribute__((ext_vector_type(8))) __bf16 bf16x8;
typedef __attribute__((ext_vector_type(4))) float f32x4;

#define IN_CH 512
#define OUT_CH 64
#define BS 98           // rows per bucket (rowres fits in 8 bits)
#define NB 512          // buckets; BS*NB = 50176 >= N
#define CHUNK 4096      // edges per scatter block (512 thr x 8)
#define CAP 4096        // fixed slots per bucket (mean 3125, +17 sigma)

__device__ inline unsigned short f2bf(float f) {
    __hip_bfloat16 h = __float2bfloat16(f);
    return __builtin_bit_cast(unsigned short, h);
}
__device__ inline float bf2f(unsigned short u) {
    return __uint_as_float(((unsigned)u) << 16);
}

// ---------------- prep: W -> MFMA B-fragments (bf16) + bcur init -------------
__global__ __launch_bounds__(512) void prep_kernel(
    const float* __restrict__ W, __hip_bfloat16* __restrict__ Wf,
    int* __restrict__ bcur)
{
    const int t = blockIdx.x * 512 + threadIdx.x;   // 0..4095
    if (t < NB) bcur[t] = t * CAP;
    const int ct = t >> 10;          // 0..3
    const int rem = t & 1023;
    const int ks = rem >> 6;         // 0..15
    const int l = rem & 63;          // lane
    const int col = ct * 16 + (l & 15);
    const int kb = ks * 32 + (l >> 4) * 8;
    __hip_bfloat16* dst = Wf + (size_t)t * 8;
    #pragma unroll
    for (int j = 0; j < 8; ++j)
        dst[j] = (__hip_bfloat16)W[(size_t)(kb + j) * OUT_CH + col];
}

// ---------------- merged: scatter blocks ++ gemm blocks ----------------------
// Blocks [0, nScatter): bucket scatter (counting sort in LDS, coalesced out).
// Blocks [nScatter, ...): 32-row GEMM tile (bf16 staged LDS, MFMA).
__global__ __launch_bounds__(512, 4) void gemmscatter_kernel(
    // scatter args
    const int* __restrict__ rows, const int* __restrict__ cols,
    const float* __restrict__ vals, int* __restrict__ bcur,
    unsigned* __restrict__ segc, unsigned char* __restrict__ segr, int E,
    int nScatter,
    // gemm args
    const float* __restrict__ A, const bf16x8* __restrict__ wf,
    __hip_bfloat16* __restrict__ outb, int N)
{
    __shared__ __align__(16) char smem[36 * 1024];
    const int tid = threadIdx.x;

    if (blockIdx.x < nScatter) {
        // ================= scatter path =================
        unsigned*       c_lds = (unsigned*)smem;                    // 16 KB
        unsigned char*  r_lds = (unsigned char*)(smem + 16384);     // 4 KB
        unsigned short* b_lds = (unsigned short*)(smem + 20480);    // 8 KB
        int* hist    = (int*)(smem + 28672);                        // 2 KB
        int* scn     = (int*)(smem + 30720);                        // 2 KB
        int* lbase   = (int*)(smem + 32768);                        // 2 KB
        int* runBase = (int*)(smem + 34816);                        // 2 KB

        const int c0 = blockIdx.x * CHUNK;
        const int cnt = min(CHUNK, E - c0);
        const int base = c0 + tid * 8;

        hist[tid] = 0;
        __syncthreads();

        int myb[8]; unsigned myc[8]; unsigned char myr[8];
        int nmine = 0;
        if (base + 8 <= E) {
            nmine = 8;
            int4 r4[2], c4[2]; float4 v4[2];
            #pragma unroll
            for (int q = 0; q < 2; ++q) {
                r4[q] = *(const int4*)(rows + base + q * 4);
                c4[q] = *(const int4*)(cols + base + q * 4);
                v4[q] = *(const float4*)(vals + base + q * 4);
            }
            #pragma unroll
            for (int q = 0; q < 2; ++q) {
                int rr[4] = {r4[q].x, r4[q].y, r4[q].z, r4[q].w};
                int cc[4] = {c4[q].x, c4[q].y, c4[q].z, c4[q].w};
                float vv[4] = {v4[q].x, v4[q].y, v4[q].z, v4[q].w};
                #pragma unroll
                for (int u = 0; u < 4; ++u) {
                    int j = q * 4 + u;
                    int r = rr[u];
                    int b = r / BS;
                    myb[j] = b;
                    myr[j] = (unsigned char)(r - b * BS);
                    myc[j] = ((unsigned)cc[u] << 16) | f2bf(vv[u]);
                    atomicAdd(&hist[b], 1);
                }
            }
        } else {
            #pragma unroll 1
            for (int j = 0; j < 8; ++j) {
                int e = base + j;
                if (e < E) {
                    int r = rows[e];
                    int b = r / BS;
                    myb[j] = b;
                    myr[j] = (unsigned char)(r - b * BS);
                    myc[j] = ((unsigned)cols[e] << 16) | f2bf(vals[e]);
                    atomicAdd(&hist[b], 1);
                    nmine = j + 1;
                }
            }
        }
        __syncthreads();

        // block-wide exclusive scan; reserve global runs
        {
            int h = hist[tid];
            scn[tid] = h;
            __syncthreads();
            for (int ofs = 1; ofs < NB; ofs <<= 1) {
                int u = 0;
                if (tid >= ofs) u = scn[tid - ofs];
                __syncthreads();
                if (tid >= ofs) scn[tid] += u;
                __syncthreads();
            }
            int excl = scn[tid] - h;
            lbase[tid] = excl;
            hist[tid] = excl;                      // reuse as local cursor
            runBase[tid] = h ? atomicAdd(&bcur[tid], h) : 0;
        }
        __syncthreads();

        #pragma unroll 1
        for (int j = 0; j < nmine; ++j) {
            int pos = atomicAdd(&hist[myb[j]], 1);
            c_lds[pos] = myc[j];
            r_lds[pos] = myr[j];
            b_lds[pos] = (unsigned short)myb[j];
        }
        __syncthreads();

        for (int idx = tid; idx < cnt; idx += 512) {
            int b = b_lds[idx];
            int gpos = runBase[b] + (idx - lbase[b]);
            segc[gpos] = c_lds[idx];
            segr[gpos] = r_lds[idx];
        }
    } else {
        // ================= gemm path =================
        char* Abf = smem;   // 32 KB: 32 rows x 1 KB, XOR-swizzled 16B blocks
        const int row0 = (blockIdx.x - nScatter) * 32;

        // staging: 4096 float4 over 512 threads (8 each), one drain
        float4 v[8];
        #pragma unroll
        for (int j = 0; j < 8; ++j) {
            int f = j * 512 + tid;
            int row = f >> 7, c4 = f & 127;
            int rg = row0 + row; rg = rg < N ? rg : N - 1;
            v[j] = *(const float4*)(A + (size_t)rg * IN_CH + c4 * 4);
        }
        #pragma unroll
        for (int j = 0; j < 8; ++j) {
            int f = j * 512 + tid;
            int row = f >> 7, c4 = f & 127;
            int blk = c4 >> 1, half = c4 & 1;
            ushort4 h;
            h.x = f2bf(v[j].x); h.y = f2bf(v[j].y);
            h.z = f2bf(v[j].z); h.w = f2bf(v[j].w);
            *(ushort4*)(Abf + row * 1024 + ((blk ^ (row & 7)) << 4) + (half << 3)) = h;
        }
        __syncthreads();

        const int lane = tid & 63;
        const int wave = tid >> 6;          // 0..7
        const int rowblk = wave & 1;        // 0..1
        const int ct = wave >> 1;           // 0..3
        const int arow = rowblk * 16 + (lane & 15);
        const int kgb = lane >> 4;

        bf16x8 a[16];
        #pragma unroll
        for (int ks = 0; ks < 16; ++ks)
            a[ks] = *(const bf16x8*)(Abf + arow * 1024 +
                                     (((ks * 4 + kgb) ^ (arow & 7)) << 4));

        f32x4 acc = {0.f, 0.f, 0.f, 0.f};
        #pragma unroll
        for (int ks = 0; ks < 16; ++ks)
            acc = __builtin_amdgcn_mfma_f32_16x16x32_bf16(
                a[ks], wf[(ct * 16 + ks) * 64 + lane], acc, 0, 0, 0);

        const int col = ct * 16 + (lane & 15);
        const int rr = row0 + rowblk * 16 + (lane >> 4) * 4;
        #pragma unroll
        for (int i = 0; i < 4; ++i) {
            int r = rr + i;
            if (r < N)
                outb[(size_t)r * OUT_CH + col] = __float2bfloat16(acc[i]);
        }
    }
}

// ---------------- fused: per-bucket sort (in place) + pass-1 SpMM ------------
__global__ __launch_bounds__(512) void sortspmm_kernel(
    const int* __restrict__ bcur,
    unsigned* __restrict__ segc, const unsigned char* __restrict__ segr,
    int* __restrict__ offs, int* __restrict__ rend,
    const __hip_bfloat16* __restrict__ x,
    __hip_bfloat16* __restrict__ y1, int N)
{
    __shared__ unsigned sorted4[CAP];      // 16 KB
    __shared__ int hist[BS + 1];
    __shared__ int cursor[BS];

    const int b = blockIdx.x;
    const int t = threadIdx.x;
    const int s = b * CAP;
    const int cnt = bcur[b] - s;

    if (t < BS + 1) hist[t] = 0;
    __syncthreads();

    unsigned ek[8]; unsigned char er[8];
    #pragma unroll
    for (int j = 0; j < 8; ++j) {
        int idx = t + j * 512;
        if (idx < cnt) {
            ek[j] = segc[s + idx];
            er[j] = segr[s + idx];
            atomicAdd(&hist[er[j]], 1);
        }
    }
    __syncthreads();

    if (t == 0) {
        int run = 0;
        for (int i = 0; i < BS; ++i) { int c = hist[i]; hist[i] = run; run += c; }
        hist[BS] = run;
    }
    __syncthreads();

    if (t < BS) {
        cursor[t] = hist[t];
        offs[b * BS + t] = s + hist[t];
        rend[b * BS + t] = s + hist[t + 1];
    }
    __syncthreads();

    #pragma unroll
    for (int j = 0; j < 8; ++j) {
        int idx = t + j * 512;
        if (idx < cnt) {
            int pos = atomicAdd(&cursor[er[j]], 1);
            sorted4[pos] = ek[j];
        }
    }
    __syncthreads();

    #pragma unroll
    for (int j = 0; j < 8; ++j) {
        int idx = t + j * 512;
        if (idx < cnt) segc[s + idx] = sorted4[idx];
    }

    // ---- pass-1 SpMM for this bucket's rows, entries from LDS ----
    const int lane = t & 63;
    const int wave = t >> 6;              // 0..7
    const int grp = lane >> 4;            // row within wave
    const int l16 = lane & 15;
    const ushort* xp = (const ushort*)x + l16 * 4;

    #pragma unroll 1
    for (int sweep = 0; sweep < 4; ++sweep) {
        int rr = sweep * 32 + wave * 4 + grp;   // row-in-bucket (0..127)
        int rrc = rr < BS ? rr : BS - 1;
        int rs = hist[rrc];
        int re = hist[rrc + 1];
        int gr = b * BS + rr;
        if (rr >= BS || gr >= N) re = rs;       // skip invalid rows

        float4 acc = {0.f, 0.f, 0.f, 0.f};
        for (int i0 = rs; i0 < re; i0 += 16) {
            unsigned p[16];
            #pragma unroll
            for (int j = 0; j < 16; ++j) {
                int idx = i0 + j;
                p[j] = sorted4[idx < re ? idx : rs];
            }
            ushort4 xv[16];
            #pragma unroll
            for (int j = 0; j < 16; ++j)
                xv[j] = *(const ushort4*)(xp + (size_t)(p[j] >> 16) * OUT_CH);
            #pragma unroll
            for (int j = 0; j < 16; ++j) {
                float wv = (i0 + j < re) ? __uint_as_float(p[j] << 16) : 0.f;
                acc.x = fmaf(wv, bf2f(xv[j].x), acc.x);
                acc.y = fmaf(wv, bf2f(xv[j].y), acc.y);
                acc.z = fmaf(wv, bf2f(xv[j].z), acc.z);
                acc.w = fmaf(wv, bf2f(xv[j].w), acc.w);
            }
        }
        if (rr < BS && gr < N) {
            ushort4 h;
            h.x = f2bf(acc.x); h.y = f2bf(acc.y);
            h.z = f2bf(acc.z); h.w = f2bf(acc.w);
            *(ushort4*)((ushort*)y1 + (size_t)gr * OUT_CH + l16 * 4) = h;
        }
    }
}

// ---------------- SpMM pass 2: 4 rows/wave (16-lane groups), 16-deep ---------
__global__ __launch_bounds__(256) void spmm_row_kernel(
    const int* __restrict__ offs, const int* __restrict__ rend,
    const unsigned* __restrict__ segc,
    const __hip_bfloat16* __restrict__ x,
    float* __restrict__ yf, const float* __restrict__ bias, int N)
{
    const int tid = threadIdx.x;
    const int lane = tid & 63;
    const int wave = tid >> 6;
    const int grp = lane >> 4;
    const int l16 = lane & 15;

    int r = (blockIdx.x * 4 + wave) * 4 + grp;
    const bool rv = r < N;
    const int rc = rv ? r : N - 1;
    const int s = offs[rc];
    const int e = rv ? rend[rc] : s;

    int m = e - s;
    m = max(m, __shfl_xor(m, 16));
    m = max(m, __shfl_xor(m, 32));
    const int iters = (m + 15) >> 4;

    const ushort* xp = (const ushort*)x + l16 * 4;

    float4 acc = {0.f, 0.f, 0.f, 0.f};
    for (int it = 0; it < iters; ++it) {
        const int base = s + it * 16;
        unsigned p[16];
        #pragma unroll
        for (int j = 0; j < 16; ++j) {
            int idx = base + j;
            p[j] = segc[idx < e ? idx : s];
        }
        ushort4 xv[16];
        #pragma unroll
        for (int j = 0; j < 16; ++j)
            xv[j] = *(const ushort4*)(xp + (size_t)(p[j] >> 16) * OUT_CH);
        #pragma unroll
        for (int j = 0; j < 16; ++j) {
            int idx = base + j;
            float wv = (idx < e) ? __uint_as_float(p[j] << 16) : 0.f;
            acc.x = fmaf(wv, bf2f(xv[j].x), acc.x);
            acc.y = fmaf(wv, bf2f(xv[j].y), acc.y);
            acc.z = fmaf(wv, bf2f(xv[j].z), acc.z);
            acc.w = fmaf(wv, bf2f(xv[j].w), acc.w);
        }
    }

    if (rv) {
        float4 bv = *(const float4*)(bias + l16 * 4);
        float4 o;
        o.x = acc.x + bv.x; o.y = acc.y + bv.y;
        o.z = acc.z + bv.z; o.w = acc.w + bv.w;
        *(float4*)(yf + (size_t)r * OUT_CH + l16 * 4) = o;
    }
}

// ---------------- launch -----------------------------------------------------
static inline size_t align_up(size_t v) { return (v + 255) & ~(size_t)255; }

extern "C" void kernel_launch(void* const* d_in, const int* in_sizes, int n_in,
                              void* d_out, int out_size, void* d_ws, size_t ws_size,
                              hipStream_t stream)
{
    const int*   adj  = (const int*)d_in[0];    // [2,E]
    const float* vals = (const float*)d_in[1];  // [E]
    const float* feat = (const float*)d_in[2];  // [N,512]
    const float* Wm   = (const float*)d_in[3];  // [512,64]
    const float* bias = (const float*)d_in[4];  // [64]

    const int E = in_sizes[1];
    const int N = in_sizes[2] / IN_CH;
    const int* rows  = adj;
    const int* colsI = adj + E;

    char* w = (char*)d_ws;
    size_t o = 0;
    __hip_bfloat16* B0b = (__hip_bfloat16*)(w + o); o += align_up((size_t)N * OUT_CH * 2);
    __hip_bfloat16* Y1b = (__hip_bfloat16*)(w + o); o += align_up((size_t)N * OUT_CH * 2);
    __hip_bfloat16* Wf  = (__hip_bfloat16*)(w + o); o += align_up((size_t)IN_CH * OUT_CH * 2);
    int*           bcur = (int*)          (w + o); o += align_up(NB * sizeof(int));
    int*           offs = (int*)          (w + o); o += align_up((size_t)NB * BS * sizeof(int));
    int*           rend = (int*)          (w + o); o += align_up((size_t)NB * BS * sizeof(int));
    unsigned*      segc = (unsigned*)     (w + o); o += align_up((size_t)NB * CAP * sizeof(unsigned));
    unsigned char* segr = (unsigned char*)(w + o); o += align_up((size_t)NB * CAP);
    (void)ws_size; (void)n_in; (void)out_size;

    // 0. W -> bf16 B-fragments, bcur init
    prep_kernel<<<8, 512, 0, stream>>>(Wm, Wf, bcur);

    // 1. merged: scatter blocks first, then gemm blocks (independent work)
    const int nScatter = (E + CHUNK - 1) / CHUNK;
    const int nGemm = (N + 31) / 32;
    gemmscatter_kernel<<<nScatter + nGemm, 512, 0, stream>>>(
        rows, colsI, vals, bcur, segc, segr, E, nScatter,
        feat, (const bf16x8*)Wf, B0b, N);

    // 2. fused per-bucket sort + pass-1 SpMM (B0b -> Y1b)
    sortspmm_kernel<<<NB, 512, 0, stream>>>(
        bcur, segc, segr, offs, rend, B0b, Y1b, N);

    // 3. pass-2 SpMM (+bias) -> d_out
    spmm_row_kernel<<<(N + 15) / 16, 256, 0, stream>>>(
        offs, rend, segc, Y1b, (float*)d_out, bias, N);
}